// Round 3
// baseline (478.870 us; speedup 1.0000x reference)
//
#include <hip/hip_runtime.h>
#include <stdint.h>

#define S_LEN 2048
#define D_DIM 128

typedef __attribute__((ext_vector_type(8))) short bf16x8;
typedef __attribute__((ext_vector_type(4))) short bf16x4;
typedef __attribute__((ext_vector_type(4))) float f32x4;

__device__ __forceinline__ short f2bf(float f) {
  union { float f; uint32_t u; } c; c.f = f;
  uint32_t u = c.u;
  u += 0x7fffu + ((u >> 16) & 1u);   // RNE to bf16
  return (short)(u >> 16);
}

// packed 2x f32 -> 2x bf16 in one 32-bit reg (low = a, high = b)
__device__ __forceinline__ uint32_t pk2bf(float a, float b) {
#if __has_builtin(__builtin_amdgcn_cvt_pk_bf16_f32)
  typedef __attribute__((ext_vector_type(2))) __bf16 bf2;
  union { bf2 v; uint32_t u; } cv;
  cv.v = __builtin_amdgcn_cvt_pk_bf16_f32(a, b);
  return cv.u;
#else
  return (uint32_t)(uint16_t)f2bf(a) | (((uint32_t)(uint16_t)f2bf(b)) << 16);
#endif
}

__device__ __forceinline__ float fexp2(float x) {
#if __has_builtin(__builtin_amdgcn_exp2f)
  return __builtin_amdgcn_exp2f(x);
#else
  return exp2f(x);
#endif
}

__device__ __forceinline__ bf16x8 mk8(uint32_t a, uint32_t b, uint32_t c, uint32_t d) {
  union { uint32_t u[4]; bf16x8 v; } x;
  x.u[0] = a; x.u[1] = b; x.u[2] = c; x.u[3] = d;
  return x.v;
}

__device__ __forceinline__ void gl_lds16(const short* g, short* l) {
  __builtin_amdgcn_global_load_lds((const __attribute__((address_space(1))) void*)g,
                                   (__attribute__((address_space(3))) void*)l, 16, 0, 0);
}

// ---------- fused preprocess: Q*scale->bf16, K->bf16, V->Vt bf16 ----------
// grid (S/128, BH), 256 threads. One 128-row tile of Q,K,V per WG.
__global__ __launch_bounds__(256) void preprocess(
    const float* __restrict__ Q, const float* __restrict__ K, const float* __restrict__ V,
    short* __restrict__ Qb, short* __restrict__ Kb, short* __restrict__ Vt) {
  __shared__ __align__(16) short sT[128 * 128];
  const int t = threadIdx.x;
  const int bh = blockIdx.y;
  const int k0 = blockIdx.x * 128;
  const size_t base = ((size_t)bh * S_LEN + k0) * D_DIM;
  const float QSCALE = 0.12751743f;  // 128^-0.5 * log2(e)

#pragma unroll
  for (int i = 0; i < 16; ++i) {
    int e = i * 1024 + t * 4;
    f32x4 v = *(const f32x4*)(Q + base + e);
    uint32_t lo = pk2bf(v[0] * QSCALE, v[1] * QSCALE);
    uint32_t hi = pk2bf(v[2] * QSCALE, v[3] * QSCALE);
    *(uint2*)(Qb + base + e) = make_uint2(lo, hi);
  }
#pragma unroll
  for (int i = 0; i < 16; ++i) {
    int e = i * 1024 + t * 4;
    f32x4 v = *(const f32x4*)(K + base + e);
    *(uint2*)(Kb + base + e) = make_uint2(pk2bf(v[0], v[1]), pk2bf(v[2], v[3]));
  }
  // V -> swizzled LDS (phys granule = (d>>3) ^ (k&15))
#pragma unroll
  for (int i = 0; i < 16; ++i) {
    int e = i * 1024 + t * 4;
    int k = e >> 7, d4 = e & 127;
    f32x4 v = *(const f32x4*)(V + base + e);
    int addr = k * 128 + (((d4 >> 3) ^ (k & 15)) << 3) + (d4 & 7);
    *(uint2*)&sT[addr] = make_uint2(pk2bf(v[0], v[1]), pk2bf(v[2], v[3]));
  }
  __syncthreads();
  const int d = t >> 1;
  const int khalf = (t & 1) * 64;
  short* out = Vt + ((size_t)bh * D_DIM + d) * S_LEN + k0 + khalf;
#pragma unroll
  for (int g = 0; g < 8; ++g) {
    bf16x8 o;
#pragma unroll
    for (int e = 0; e < 8; ++e) {
      int k = khalf + g * 8 + e;
      o[e] = sT[k * 128 + (((d >> 3) ^ (k & 15)) << 3) + (d & 7)];
    }
    *(bf16x8*)(out + g * 8) = o;
  }
}

// ---------- main blocked-attention kernel ----------
// WG 256 / 4 waves, 64 q-rows. Wave (qh,h): q-half qh (32 rows), key-half h (32/chunk).
// S^T = K*Q^T so P stays register-resident (C-layout -> A-frag via pk-pack only).
// K/Vt stream through 4x16KB LDS ring, global_load_lds(16B), capacity-floor swizzles.
__global__ __launch_bounds__(256, 2) void attn_main(
    const short* __restrict__ Qb, const short* __restrict__ Kb,
    const short* __restrict__ Vt, float* __restrict__ O) {
  __shared__ __align__(16) short ring[4][8192];  // 64 KB
  __shared__ float sRed[128];                    // [64 q][2 h]

  const int t = threadIdx.x;
  const int w = t >> 6;
  const int lane = t & 63;
  const int l15 = lane & 15;
  const int quad = lane >> 4;
  const int h = w & 1;    // key-half
  const int qh = w >> 1;  // q-half
  const int bh = blockIdx.y;
  const int q0 = blockIdx.x * 64;

  const short* Kh = Kb + (size_t)bh * S_LEN * D_DIM;
  const short* Vh = Vt + (size_t)bh * D_DIM * S_LEN;

  // staging constants (16-wide K granule swizzle, 8-wide V granule swizzle)
  const int kKey = t >> 4;
  const int kG = (t & 15) ^ (kKey & 15);
  const int vD = t >> 3;
  const int vG = (t & 7) ^ (vD & 7);

  auto stageK = [&](int key0, int slot) {
    const short* src = Kh + (size_t)(key0 + kKey) * D_DIM + kG * 8;
    short* dst = &ring[slot][t * 8];
#pragma unroll
    for (int r = 0; r < 4; ++r) gl_lds16(src + r * 16 * D_DIM, dst + r * 2048);
  };
  auto stageV = [&](int key0, int slot) {
    const short* src = Vh + (size_t)vD * S_LEN + key0 + vG * 8;
    short* dst = &ring[slot][t * 8];
#pragma unroll
    for (int r = 0; r < 4; ++r) gl_lds16(src + (size_t)r * 32 * S_LEN, dst + r * 2048);
  };

  // Q fragments (register-resident): B-operand of S^T = K*Q^T
  bf16x8 qf[2][4];
  {
    const short* Qh = Qb + ((size_t)bh * S_LEN + q0 + qh * 32) * D_DIM;
#pragma unroll
    for (int nt = 0; nt < 2; ++nt)
#pragma unroll
      for (int ks = 0; ks < 4; ++ks)
        qf[nt][ks] = *(const bf16x8*)(Qh + (nt * 16 + l15) * D_DIM + ks * 32 + quad * 8);
  }

  // K A-frag LDS offsets: key = h*32 + mtk*16 + l15, granule swz with key&15 = l15
  int kAoff[2][4];
#pragma unroll
  for (int mtk = 0; mtk < 2; ++mtk)
#pragma unroll
    for (int ks = 0; ks < 4; ++ks)
      kAoff[mtk][ks] = (h * 32 + mtk * 16 + l15) * 128 + (((ks * 4 + quad) ^ l15) << 3);

  // V B-frag LDS offsets: row d, two b64 at key offsets h*32+quad*4 (+0 / +16)
  int vBoff[8][2];
#pragma unroll
  for (int ntd = 0; ntd < 8; ++ntd) {
    int d = ntd * 16 + l15;
#pragma unroll
    for (int s = 0; s < 2; ++s)
      vBoff[ntd][s] = d * 64 + (((4 * h + 2 * s + (quad >> 1)) ^ (d & 7)) << 3) + 4 * (quad & 1);
  }

  f32x4 oa[2][8];
#pragma unroll
  for (int a = 0; a < 2; ++a)
#pragma unroll
    for (int b = 0; b < 8; ++b) oa[a][b] = (f32x4){0.f, 0.f, 0.f, 0.f};

  // prologue: first three K chunks
  stageK(0, 0); stageK(64, 1); stageK(128, 2);

  for (int j = 0; j < 8; ++j) {
    const int jb = j * 256;
    f32x4 sc[4][2][2];  // [chunk][key-tile][q-tile]
#pragma unroll
    for (int c = 0; c < 4; ++c)
#pragma unroll
      for (int a = 0; a < 2; ++a)
#pragma unroll
        for (int b = 0; b < 2; ++b) sc[c][a][b] = (f32x4){0.f, 0.f, 0.f, 0.f};

    // ---- S^T phase: 4 chunks of 64 keys ----
#pragma unroll
    for (int c = 0; c < 4; ++c) {
      __syncthreads();
      if (c == 0) stageK(jb + 192, 3);
      else        stageV(jb + (c - 1) * 64, c - 1);
      const short* buf = &ring[c][0];
#pragma unroll
      for (int ks = 0; ks < 4; ++ks) {
        bf16x8 a0 = *(const bf16x8*)(buf + kAoff[0][ks]);
        bf16x8 a1 = *(const bf16x8*)(buf + kAoff[1][ks]);
        sc[c][0][0] = __builtin_amdgcn_mfma_f32_16x16x32_bf16(a0, qf[0][ks], sc[c][0][0], 0, 0, 0);
        sc[c][0][1] = __builtin_amdgcn_mfma_f32_16x16x32_bf16(a0, qf[1][ks], sc[c][0][1], 0, 0, 0);
        sc[c][1][0] = __builtin_amdgcn_mfma_f32_16x16x32_bf16(a1, qf[0][ks], sc[c][1][0], 0, 0, 0);
        sc[c][1][1] = __builtin_amdgcn_mfma_f32_16x16x32_bf16(a1, qf[1][ks], sc[c][1][1], 0, 0, 0);
      }
    }

    // ---- softmax over this 256-key block (Q prescaled by scale*log2e) ----
#pragma unroll
    for (int c = 0; c < 4; ++c)
#pragma unroll
      for (int a = 0; a < 2; ++a)
#pragma unroll
        for (int b = 0; b < 2; ++b)
#pragma unroll
          for (int r = 0; r < 4; ++r) sc[c][a][b][r] = fexp2(sc[c][a][b][r]);

    f32x4 s0 = (sc[0][0][0] + sc[1][0][0]) + (sc[2][0][0] + sc[3][0][0]);
    f32x4 s0b = (sc[0][1][0] + sc[1][1][0]) + (sc[2][1][0] + sc[3][1][0]);
    s0 += s0b;
    f32x4 s1 = (sc[0][0][1] + sc[1][0][1]) + (sc[2][0][1] + sc[3][0][1]);
    f32x4 s1b = (sc[0][1][1] + sc[1][1][1]) + (sc[2][1][1] + sc[3][1][1]);
    s1 += s1b;
    float p0 = (s0[0] + s0[1]) + (s0[2] + s0[3]);
    float p1 = (s1[0] + s1[1]) + (s1[2] + s1[3]);
    p0 += __shfl_xor(p0, 16); p0 += __shfl_xor(p0, 32);
    p1 += __shfl_xor(p1, 16); p1 += __shfl_xor(p1, 32);
    if (quad == 0) {
      sRed[(qh * 32 + l15) * 2 + h] = p0;
      sRed[(qh * 32 + 16 + l15) * 2 + h] = p1;
    }
    __syncthreads();
    stageV(jb + 192, 3);
    float linv0 = __fdividef(1.0f, p0 + sRed[(qh * 32 + l15) * 2 + (1 - h)]);
    float linv1 = __fdividef(1.0f, p1 + sRed[(qh * 32 + 16 + l15) * 2 + (1 - h)]);

    // ---- P -> A-fragments, fully in-register ----
    // frag element (quad,j) <-> key h*32 + (j>>2)*16 + quad*4 + (j&3) within chunk g
    bf16x8 pf[2][4];
#pragma unroll
    for (int ntq = 0; ntq < 2; ++ntq) {
      float li = ntq ? linv1 : linv0;
#pragma unroll
      for (int g = 0; g < 4; ++g) {
        f32x4 u = sc[g][0][ntq];
        f32x4 v = sc[g][1][ntq];
        pf[ntq][g] = mk8(pk2bf(u[0] * li, u[1] * li), pk2bf(u[2] * li, u[3] * li),
                         pk2bf(v[0] * li, v[1] * li), pk2bf(v[2] * li, v[3] * li));
      }
    }

    // ---- PV phase: 4 chunks of 64 keys ----
#pragma unroll
    for (int g = 0; g < 4; ++g) {
      __syncthreads();
      if (g >= 1 && j < 7) stageK(jb + 256 + (g - 1) * 64, g - 1);
      const short* buf = &ring[g][0];
#pragma unroll
      for (int ntd = 0; ntd < 8; ++ntd) {
        bf16x4 b0 = *(const bf16x4*)(buf + vBoff[ntd][0]);
        bf16x4 b1 = *(const bf16x4*)(buf + vBoff[ntd][1]);
        union { bf16x4 hv[2]; bf16x8 v; } bb;
        bb.hv[0] = b0; bb.hv[1] = b1;
        oa[0][ntd] = __builtin_amdgcn_mfma_f32_16x16x32_bf16(pf[0][g], bb.v, oa[0][ntd], 0, 0, 0);
        oa[1][ntd] = __builtin_amdgcn_mfma_f32_16x16x32_bf16(pf[1][g], bb.v, oa[1][ntd], 0, 0, 0);
      }
    }
  }

  // ---- tail: add partner wave's key-half partial (exchange via ring LDS) ----
  __syncthreads();
  float* red = (float*)&ring[0][0];
  float* myreg = red + w * 2080;  // [32 q][64 d] stride 65
  const int nbase = h ? 0 : 4;    // non-owned d ntds I write
#pragma unroll
  for (int ntq = 0; ntq < 2; ++ntq)
#pragma unroll
    for (int ntd = 0; ntd < 4; ++ntd)
#pragma unroll
      for (int r = 0; r < 4; ++r)
        myreg[(ntq * 16 + quad * 4 + r) * 65 + ntd * 16 + l15] = oa[ntq][nbase + ntd][r];
  __syncthreads();
  const float* pr = red + (w ^ 1) * 2080;
  const int oidx = h ? 4 : 0;
  const int obase = h * 64;
  float* Og = O + ((size_t)bh * S_LEN + q0 + qh * 32) * D_DIM;
#pragma unroll
  for (int ntq = 0; ntq < 2; ++ntq)
#pragma unroll
    for (int ntd = 0; ntd < 4; ++ntd)
#pragma unroll
      for (int r = 0; r < 4; ++r) {
        float val = oa[ntq][oidx + ntd][r] + pr[(ntq * 16 + quad * 4 + r) * 65 + ntd * 16 + l15];
        Og[(ntq * 16 + quad * 4 + r) * D_DIM + obase + ntd * 16 + l15] = val;
      }
}

extern "C" void kernel_launch(void* const* d_in, const int* in_sizes, int n_in,
                              void* d_out, int out_size, void* d_ws, size_t ws_size,
                              hipStream_t stream) {
  const float* Q = (const float*)d_in[0];
  const float* K = (const float*)d_in[1];
  const float* V = (const float*)d_in[2];
  float* Out = (float*)d_out;
  const int bhN = in_sizes[0] / (S_LEN * D_DIM);  // 32
  const size_t tElems = (size_t)bhN * S_LEN * D_DIM;

  short* Qb = (short*)d_ws;
  short* Kb = Qb + tElems;
  short* Vtb = Kb + tElems;

  preprocess<<<dim3(S_LEN / 128, bhN), 256, 0, stream>>>(Q, K, V, Qb, Kb, Vtb);
  attn_main<<<dim3(S_LEN / 64, bhN), 256, 0, stream>>>(Qb, Kb, Vtb, Out);
}

// Round 5
// 240.078 us; speedup vs baseline: 1.9946x; 1.9946x over previous
//
#include <hip/hip_runtime.h>
#include <stdint.h>

#define S_LEN 2048
#define D_DIM 128

typedef __attribute__((ext_vector_type(8)))  short bf16x8;
typedef __attribute__((ext_vector_type(4)))  short bf16x4;
typedef __attribute__((ext_vector_type(4)))  float f32x4;
typedef __attribute__((ext_vector_type(2)))  float f32x2;
typedef __attribute__((ext_vector_type(16))) float f32x16;

__device__ __forceinline__ short f2bf(float f) {
  union { float f; uint32_t u; } c; c.f = f;
  uint32_t u = c.u;
  u += 0x7fffu + ((u >> 16) & 1u);
  return (short)(u >> 16);
}
__device__ __forceinline__ uint32_t pk2bf(float a, float b) {
#if __has_builtin(__builtin_amdgcn_cvt_pk_bf16_f32)
  typedef __attribute__((ext_vector_type(2))) __bf16 bf2;
  union { bf2 v; uint32_t u; } cv;
  cv.v = __builtin_amdgcn_cvt_pk_bf16_f32(a, b);
  return cv.u;
#else
  return (uint32_t)(uint16_t)f2bf(a) | (((uint32_t)(uint16_t)f2bf(b)) << 16);
#endif
}
__device__ __forceinline__ bf16x8 mk8(uint32_t a, uint32_t b, uint32_t c, uint32_t d) {
  union { uint32_t u[4]; bf16x8 v; } x;
  x.u[0] = a; x.u[1] = b; x.u[2] = c; x.u[3] = d;
  return x.v;
}
__device__ __forceinline__ void gl_lds16(const short* g, short* l) {
  __builtin_amdgcn_global_load_lds((const __attribute__((address_space(1))) void*)g,
                                   (__attribute__((address_space(3))) void*)l, 16, 0, 0);
}

// ---------------- preprocess ----------------
// blocks [0,2048): K fp32->bf16 linear.  blocks [2048,2560): V -> Vt bf16,
// transposed to [bh][d][key], with keys bit-swapped (b2<->b3 per 16-group) so
// PV B-fragments match the in-register P A-fragment key permutation.
__global__ __launch_bounds__(256) void pre_kernel(
    const float* __restrict__ K, const float* __restrict__ V,
    short* __restrict__ Kb, short* __restrict__ Vt) {
  const int t = threadIdx.x;
  if (blockIdx.x < 2048) {
    int i0 = blockIdx.x * 256 + t;
#pragma unroll
    for (int r = 0; r < 4; ++r) {
      int i = i0 + r * 524288;
      f32x4 v = ((const f32x4*)K)[i];
      *(uint2*)(Kb + (size_t)i * 4) = make_uint2(pk2bf(v[0], v[1]), pk2bf(v[2], v[3]));
    }
    return;
  }
  __shared__ __align__(16) short sTt[128 * 128];  // [d][swizzled k granules] 16 granules/row
  const int vb = blockIdx.x - 2048;
  const int bh = vb >> 4;
  const int k0 = (vb & 15) * 128;
  const float* src = V + ((size_t)bh * S_LEN + k0) * D_DIM;
#pragma unroll
  for (int i = 0; i < 16; ++i) {
    int e = i * 1024 + t * 4;
    int k = e >> 7, d4 = e & 127;
    f32x4 v = *(const f32x4*)(src + e);
#pragma unroll
    for (int jj = 0; jj < 4; ++jj) {
      int d = d4 + jj;
      sTt[d * 128 + (((k >> 3) ^ (d & 15)) << 3) + (k & 7)] = f2bf(v[jj]);
    }
  }
  __syncthreads();
  const int d = t >> 1;
  const int ph = (t & 1) * 64;
  short* out = Vt + ((size_t)bh * D_DIM + d) * S_LEN + k0 + ph;
#pragma unroll
  for (int g = 0; g < 8; ++g) {
    int pb = ph + g * 8;
    int B = pb >> 4;
    int rlo = pb & 15;                     // 0 or 8
    int kb1 = B * 16 + (rlo ? 4 : 0);
    int kb2 = kb1 + 8;
    bf16x4 lo = *(const bf16x4*)&sTt[d * 128 + (((kb1 >> 3) ^ (d & 15)) << 3) + (kb1 & 7)];
    bf16x4 hi = *(const bf16x4*)&sTt[d * 128 + (((kb2 >> 3) ^ (d & 15)) << 3) + (kb2 & 7)];
    union { bf16x4 h[2]; bf16x8 v; } o;
    o.h[0] = lo; o.h[1] = hi;
    *(bf16x8*)(out + g * 8) = o.v;
  }
}

// ---------------- main kernel ----------------
// WG 256 / 4 waves = (qp: q-half of 32, h: key-interleave). 64 q-rows/WG.
// Per 64-key chunk: S^T=K*Q^T (32x32x16, wave owns keys [h*32,h*32+32)), exp2,
// pack UNNORMALIZED P to A-frags in-register (key perm = bit2<->bit3, matched
// by Vt pre-permutation), 8KB sP exchange, PV into oj.
// Per 256-key block: oa += oj * (1/rowsum). K/V double-buffered via
// global_load_lds(16B) with granule-XOR swizzle.
__global__ __launch_bounds__(256, 2) void attn_main(
    const short* __restrict__ Kb, const short* __restrict__ Vt,
    const float* __restrict__ Q, float* __restrict__ O) {
  __shared__ __align__(16) short ring[2][16384];  // per slot: K 16KB | V 16KB
  __shared__ __align__(16) short sP[4096];        // 8 regions x 512 (qp,hw,t2)
  __shared__ float sRed[128];                     // [64 q][2 h]
  __shared__ float sLinv[64];
  // total LDS = 65536 + 8192 + 512 + 256 = 74496 B -> 2 blocks/CU

  const int t = threadIdx.x;
  const int w = t >> 6;
  const int lane = t & 63;
  const int l31 = lane & 31;
  const int hi = lane >> 5;
  const int h = w & 1;
  const int qp = w >> 1;

  // XCD swizzle: bh = (b&7)*4 + ((b>>3)&3), qtile = b>>5
  const int b = blockIdx.x;
  const int bh = (b & 7) * 4 + ((b >> 3) & 3);
  const int q0 = (b >> 5) * 64;

  const short* Kh = Kb + (size_t)bh * S_LEN * D_DIM;
  const short* Vh = Vt + (size_t)bh * D_DIM * S_LEN;

  // staging constants (K rows: 16 granules, mask 15; V rows: 8 granules, mask 7)
  const int kKey = t >> 4;                       // + r*16
  const int kG   = (t & 15) ^ (kKey & 15);
  const int vD   = t >> 3;                       // + r*32
  const int vG   = (t & 7) ^ (vD & 7);

  auto stageK = [&](int key0, int slot) {
    const short* src = Kh + (size_t)(key0 + kKey) * D_DIM + kG * 8;
    short* dst = &ring[slot][t * 8];
#pragma unroll
    for (int r = 0; r < 4; ++r) gl_lds16(src + r * 16 * D_DIM, dst + r * 2048);
  };
  auto stageV = [&](int key0, int slot) {
    const short* src = Vh + (size_t)vD * S_LEN + key0 + vG * 8;
    short* dst = &ring[slot][8192 + t * 8];
#pragma unroll
    for (int r = 0; r < 4; ++r) gl_lds16(src + (size_t)r * 32 * S_LEN, dst + r * 2048);
  };

  // ---- Q fragments: load fp32, scale, pack (register-resident) ----
  bf16x8 qf[8];
  {
    const float QSCALE = 0.12751743f;  // 128^-0.5 * log2(e)
    const float* Qg = Q + ((size_t)bh * S_LEN + q0 + qp * 32 + l31) * D_DIM;
#pragma unroll
    for (int ks = 0; ks < 8; ++ks) {
      f32x4 a = *(const f32x4*)(Qg + ks * 16 + hi * 8);
      f32x4 c = *(const f32x4*)(Qg + ks * 16 + hi * 8 + 4);
      qf[ks] = mk8(pk2bf(a[0] * QSCALE, a[1] * QSCALE), pk2bf(a[2] * QSCALE, a[3] * QSCALE),
                   pk2bf(c[0] * QSCALE, c[1] * QSCALE), pk2bf(c[2] * QSCALE, c[3] * QSCALE));
    }
  }

  // K A-frag LDS offsets (shorts): row = h*32+l31, logical granule 2ks+hi
  int aK[8];
#pragma unroll
  for (int ks = 0; ks < 8; ++ks)
    aK[ks] = (h * 32 + l31) * 128 + (((2 * ks + hi) ^ (l31 & 15)) << 3);
  // V B-frag LDS offsets: row d = h*64 (+dt*32) + l31, logical granule u*2+hi
  int aV[4];
#pragma unroll
  for (int u = 0; u < 4; ++u)
    aV[u] = (h * 64 + l31) * 64 + (((u * 2 + hi) ^ (l31 & 7)) << 3);

  f32x16 oa[2], oj[2];
#pragma unroll
  for (int d = 0; d < 2; ++d)
#pragma unroll
    for (int r = 0; r < 16; ++r) { oa[d][r] = 0.f; oj[d][r] = 0.f; }

  float ssum = 0.f;
  const int spOwn = ((qp * 2 + h) * 2) * 512 + lane * 8;

  stageK(0, 0); stageV(0, 0);

  for (int j = 0; j < 8; ++j) {
#pragma unroll
    for (int c = 0; c < 4; ++c) {
      const int G = j * 4 + c;
      const int slot = G & 1;
      __syncthreads();  // chunk G staged; sP(G-1) consumed; ring[slot^1] free
      if (G + 1 < 32) { stageK((G + 1) * 64, slot ^ 1); stageV((G + 1) * 64, slot ^ 1); }

      if (c == 0 && j > 0) {
        // normalize previous block: oa += oj * linv (then clear oj)
        f32x4 lv[4];
#pragma unroll
        for (int g = 0; g < 4; ++g) lv[g] = *(const f32x4*)&sLinv[qp * 32 + g * 8 + hi * 4];
#pragma unroll
        for (int d = 0; d < 2; ++d)
#pragma unroll
          for (int r = 0; r < 16; ++r) {
            oa[d][r] += oj[d][r] * lv[r >> 2][r & 3];
            oj[d][r] = 0.f;
          }
      }

      // ---- QK^T: one 32x32 tile (wave's keys: chunk G, [h*32, h*32+32)) ----
      const short* pK = &ring[slot][0];
      f32x16 sc;
#pragma unroll
      for (int r = 0; r < 16; ++r) sc[r] = 0.f;
#pragma unroll
      for (int ks = 0; ks < 8; ++ks) {
        bf16x8 a = *(const bf16x8*)(pK + aK[ks]);
        sc = __builtin_amdgcn_mfma_f32_32x32x16_bf16(a, qf[ks], sc, 0, 0, 0);
      }
#pragma unroll
      for (int r = 0; r < 16; ++r) sc[r] = exp2f(sc[r]);
      float ps = 0.f;
#pragma unroll
      for (int r = 0; r < 16; ++r) ps += sc[r];
      ssum += ps;

      // pack unnormalized P to A-frags; write to sP
      bf16x8 pf[2];
#pragma unroll
      for (int t2 = 0; t2 < 2; ++t2) {
        pf[t2] = mk8(pk2bf(sc[8 * t2 + 0], sc[8 * t2 + 1]), pk2bf(sc[8 * t2 + 2], sc[8 * t2 + 3]),
                     pk2bf(sc[8 * t2 + 4], sc[8 * t2 + 5]), pk2bf(sc[8 * t2 + 6], sc[8 * t2 + 7]));
        *(bf16x8*)(sP + spOwn + t2 * 512) = pf[t2];
      }
      if (c == 3) {
        ssum += __shfl_xor(ssum, 32);
        if (lane < 32) sRed[(qp * 32 + l31) * 2 + h] = ssum;
        ssum = 0.f;
      }
      __syncthreads();  // sP ready (+ sRed at c==3)
      if (c == 3 && h == 0 && lane < 32) {
        f32x2 s2 = *(const f32x2*)&sRed[(qp * 32 + l31) * 2];
        sLinv[qp * 32 + l31] = __fdividef(1.0f, s2[0] + s2[1]);
      }

      // ---- PV: 4 (hw,t2) ksteps x 2 d-tiles ----
      const short* pV = &ring[slot][8192];
#pragma unroll
      for (int hw = 0; hw < 2; ++hw)
#pragma unroll
        for (int t2 = 0; t2 < 2; ++t2) {
          bf16x8 a = (hw == h) ? pf[t2]
                               : *(const bf16x8*)(sP + ((qp * 2 + hw) * 2 + t2) * 512 + lane * 8);
#pragma unroll
          for (int dt = 0; dt < 2; ++dt) {
            bf16x8 bv = *(const bf16x8*)(pV + aV[hw * 2 + t2] + dt * 2048);
            oj[dt] = __builtin_amdgcn_mfma_f32_32x32x16_bf16(a, bv, oj[dt], 0, 0, 0);
          }
        }
    }
  }

  __syncthreads();
  // final normalize + store
  {
    f32x4 lv[4];
#pragma unroll
    for (int g = 0; g < 4; ++g) lv[g] = *(const f32x4*)&sLinv[qp * 32 + g * 8 + hi * 4];
    float* Og = O + ((size_t)bh * S_LEN + q0) * D_DIM;
#pragma unroll
    for (int d = 0; d < 2; ++d)
#pragma unroll
      for (int r = 0; r < 16; ++r) {
        float val = oa[d][r] + oj[d][r] * lv[r >> 2][r & 3];
        int row = qp * 32 + (r & 3) + 8 * (r >> 2) + 4 * hi;
        int col = h * 64 + d * 32 + l31;
        Og[row * D_DIM + col] = val;
      }
  }
}

extern "C" void kernel_launch(void* const* d_in, const int* in_sizes, int n_in,
                              void* d_out, int out_size, void* d_ws, size_t ws_size,
                              hipStream_t stream) {
  const float* Q = (const float*)d_in[0];
  const float* K = (const float*)d_in[1];
  const float* V = (const float*)d_in[2];
  float* Out = (float*)d_out;
  const size_t tElems = (size_t)32 * S_LEN * D_DIM;

  short* Kb  = (short*)d_ws;
  short* Vtb = Kb + tElems;

  pre_kernel<<<2560, 256, 0, stream>>>(K, V, Kb, Vtb);
  attn_main<<<1024, 256, 0, stream>>>(Kb, Vtb, Q, Out);
}